// Round 12
// baseline (121.993 us; speedup 1.0000x reference)
//
#include <hip/hip_runtime.h>

// DilateAttention: B=4, d=384 (12 heads x 32), H=W=64, 3x3 taps, dilation 2, pad 2.
// f32 in / f32 out.
// v13: chunked double-buffered global_load_lds pipeline.
// v12 post-mortem: 64-KB monolithic LDS capped residency at 2 blocks/CU
// (8 waves/CU) and exposed the v-DMA flight behind one softmax — it tested
// low-occupancy DMA, not a pipeline. v13 keeps v12's validated pieces
// (DMA staging, post-hoc tap gating, v1's per-lane 128-B stores, bijective
// XCD swizzle) and restructures:
//   - chunk = 8 ch x 6 rows x 64 x = 12 KB; 2 buffers = 24 KB -> 6 blocks/CU.
//   - block = 128 threads (2 waves = 2 query rows), grid = B*NH*32 = 1536
//     = 8 XCDs x 192 -> exactly 6 resident blocks/CU, 12 waves/CU (1.5x v12).
//   - 8-phase prefetch-ahead-one: STAGE(next buf) right after the barrier
//     that frees it; each flight hides under one chunk's 72 LDS reads + FMAs.
//   - LDS taps read as rp[-2]/rp[0]/rp[2] off one base (unclamped, post-hoc
//     gated like v12; OOB LDS reads return garbage/0 but cannot fault) ->
//     compiler fuses ds_read2_b32, ~1.5x off the dominant DS-pipe term.

#define NHD  12
#define DDIM 384
#define HH   64
#define WW   64
#define HWSZ 4096
#define SCALEF 0.17677669529663687f  // 1/sqrt(32)
#define CF 3072                      // floats per chunk buffer (8*6*64) = 12 KB

typedef __attribute__((address_space(3))) char  lds_char;
typedef __attribute__((address_space(1))) void  gvoid;

__global__ __launch_bounds__(128) void dilate_attn(const float* __restrict__ q,
                                                   const float* __restrict__ k,
                                                   const float* __restrict__ v,
                                                   float* __restrict__ out) {
    __shared__ float bufA[CF];
    __shared__ float bufB[CF];

    const int tid = threadIdx.x;
    const int r   = tid >> 6;            // query row within block (wave id, 0..1)
    const int x   = tid & 63;            // lane = x

    // XCD swizzle: 1536 = 8 XCDs x 192 contiguous logical blocks (bijective).
    const int phys = blockIdx.x;
    const int lz   = (phys & 7) * 192 + (phys >> 3);
    const int bh   = lz >> 5;            // b*NH + n
    const int y0   = (lz & 31) * 2;
    const int y    = y0 + r;
    const int b    = bh / NHD;
    const int n    = bh - b * NHD;

    const int cbase = (b * DDIM + n * 32) * HWSZ;   // 32-bit element indexing
    const int pix   = y * WW + x;

    // Staging descriptors: 6 DMA instrs per wave per 12-KB chunk.
    // flat float index f0 = (r*6+i)*256 + lane*4 -> [ch8][row][x4] of the chunk;
    // LDS byte = f0*4 = uniform (r*6+i)*1024 + lane*16 (DMA dest constraint).
    int goff[6];
#pragma unroll
    for (int i = 0; i < 6; ++i) {
        const int f0  = (r * 6 + i) * 256 + x * 4;
        const int ch8 = f0 / 384;
        const int rem = f0 - ch8 * 384;
        const int row = rem >> 6;
        const int x4  = rem & 63;
        int gy = y0 - 2 + row;           // halo row, clamped (taps gated later)
        gy = gy < 0 ? 0 : (gy > 63 ? 63 : gy);
        goff[i] = ch8 * HWSZ + gy * WW + x4;
    }

    // Tap validity (post-hoc gating semantics, validated v1-v12).
    bool vy[3];
#pragma unroll
    for (int di = 0; di < 3; ++di) {
        const int yy = y + 2 * di - 2;
        vy[di] = (yy >= 0) && (yy < HH);
    }
    const bool vxm = (x >= 2), vxp = (x <= 61);
    bool tval[9];
#pragma unroll
    for (int di = 0; di < 3; ++di) {
        tval[di * 3 + 0] = vy[di] && vxm;
        tval[di * 3 + 1] = vy[di];
        tval[di * 3 + 2] = vy[di] && vxp;
    }

#define STAGE(TB, CH, BUF) do {                                                   \
    const float* _tb = (TB) + cbase + (CH) * 8 * HWSZ;                            \
    _Pragma("unroll")                                                             \
    for (int i = 0; i < 6; ++i) {                                                 \
        __builtin_amdgcn_global_load_lds(                                         \
            (const gvoid*)(_tb + goff[i]),                                        \
            (__attribute__((address_space(3))) void*)((lds_char*)(BUF) +          \
                                                      (r * 6 + i) * 1024),        \
            16, 0, 0);                                                            \
    } } while (0)

#define QKC(CH, BUF) do {                                                         \
    _Pragma("unroll")                                                             \
    for (int c8 = 0; c8 < 8; ++c8) {                                              \
        const float qc = qreg[(CH) * 8 + c8];                                     \
        _Pragma("unroll")                                                         \
        for (int di = 0; di < 3; ++di) {                                          \
            const float* rp = &(BUF)[c8 * 384 + (r + 2 * di) * 64 + x];           \
            l[di * 3 + 0] += qc * rp[-2];                                         \
            l[di * 3 + 1] += qc * rp[0];                                          \
            l[di * 3 + 2] += qc * rp[2];                                          \
        } } } while (0)

#define PVC(CH, BUF) do {                                                         \
    _Pragma("unroll")                                                             \
    for (int c8 = 0; c8 < 8; ++c8) {                                              \
        float acc = 0.f;                                                          \
        _Pragma("unroll")                                                         \
        for (int di = 0; di < 3; ++di) {                                          \
            const float* rp = &(BUF)[c8 * 384 + (r + 2 * di) * 64 + x];           \
            acc += w[di * 3 + 0] * rp[-2] + w[di * 3 + 1] * rp[0]                 \
                 + w[di * 3 + 2] * rp[2];                                         \
        }                                                                         \
        o[(CH) * 8 + c8] = acc;                                                   \
    } } while (0)

    // ---------------- prologue: prefetch k0,k1; q preload overlaps ----------
    STAGE(k, 0, bufA);
    STAGE(k, 1, bufB);

    float qreg[32];
#pragma unroll
    for (int c = 0; c < 32; ++c) qreg[c] = q[cbase + pix + c * HWSZ] * SCALEF;

    float l[9];
#pragma unroll
    for (int t = 0; t < 9; ++t) l[t] = 0.f;

    __syncthreads();          // k0,k1,q landed
    QKC(0, bufA);
    __syncthreads();          // A free
    STAGE(k, 2, bufA);
    QKC(1, bufB);
    __syncthreads();          // B free; k2 landed (flight hid under QK1)
    STAGE(k, 3, bufB);
    QKC(2, bufA);
    __syncthreads();          // A free; k3 landed
    STAGE(v, 0, bufA);
    QKC(3, bufB);
    __syncthreads();          // B free; v0 landed (flight hid under QK3)
    STAGE(v, 1, bufB);

    // ---------------- softmax over 9 (v1 flight hides under this + PV0) -----
#pragma unroll
    for (int t = 0; t < 9; ++t) l[t] = tval[t] ? l[t] : 0.f;   // zero-pad taps
    float m = l[0];
#pragma unroll
    for (int t = 1; t < 9; ++t) m = fmaxf(m, l[t]);
    float w[9], s = 0.f;
#pragma unroll
    for (int t = 0; t < 9; ++t) { w[t] = __expf(l[t] - m); s += w[t]; }
    const float inv = 1.0f / s;
#pragma unroll
    for (int t = 0; t < 9; ++t) w[t] = tval[t] ? (w[t] * inv) : 0.f;  // pad V == 0

    float o[32];
    PVC(0, bufA);
    __syncthreads();          // A free; v1 landed
    STAGE(v, 2, bufA);
    PVC(1, bufB);
    __syncthreads();          // B free; v2 landed
    STAGE(v, 3, bufB);
    PVC(2, bufA);
    __syncthreads();          // v3 landed
    PVC(3, bufB);

    // ---------------- Output: lane owns the full 128-B head chunk -----------
    const int ob = (b * HH * WW + pix) * DDIM + n * 32;
#pragma unroll
    for (int j = 0; j < 8; ++j)
        *(float4*)(out + ob + j * 4) =
            make_float4(o[j * 4], o[j * 4 + 1], o[j * 4 + 2], o[j * 4 + 3]);
}

extern "C" void kernel_launch(void* const* d_in, const int* in_sizes, int n_in,
                              void* d_out, int out_size, void* d_ws, size_t ws_size,
                              hipStream_t stream) {
    const float* q = (const float*)d_in[0];
    const float* k = (const float*)d_in[1];
    const float* v = (const float*)d_in[2];
    float* out = (float*)d_out;
    hipLaunchKernelGGL(dilate_attn, dim3(1536), dim3(128), 0, stream, q, k, v, out);
}